// Round 18
// baseline (203.706 us; speedup 1.0000x reference)
//
#include <hip/hip_runtime.h>
#include <stdint.h>

#define NB 4
#define NS 2048
#define ND 1024
#define NH 16
#define NDK 64
#define NM (NB*NS)   // 8192 rows total

typedef __attribute__((ext_vector_type(8))) short short8;
typedef __attribute__((ext_vector_type(8))) unsigned short ushort8v;
typedef __attribute__((ext_vector_type(4))) float f32x4;
typedef __attribute__((ext_vector_type(16))) float f32x16;

__device__ __forceinline__ unsigned short f2bf(float f) {
  union { float f; uint32_t u; } v; v.f = f;
  uint32_t u = v.u;
  return (unsigned short)((u + 0x7FFFu + ((u >> 16) & 1u)) >> 16);
}

__device__ __forceinline__ void gload16(const void* g, void* l) {
  __builtin_amdgcn_global_load_lds(
      (const __attribute__((address_space(1))) void*)g,
      (__attribute__((address_space(3))) void*)l, 16, 0, 0);
}

// T1: bijective XCD swizzle (requires nwg % 8 == 0)
__device__ __forceinline__ int xcd_swz(int flat, int nwg) {
  return (flat & 7) * (nwg >> 3) + (flat >> 3);
}

// ---------------- fused conversion fp32 -> bf16 (q,k,v + 4 weights) ----------------
__global__ void convert_all(
    const float* __restrict__ x0, const float* __restrict__ x1, const float* __restrict__ x2,
    const float* __restrict__ w0, const float* __restrict__ w1,
    const float* __restrict__ w2, const float* __restrict__ w3,
    unsigned short* __restrict__ ox0, unsigned short* __restrict__ ox1, unsigned short* __restrict__ ox2,
    unsigned short* __restrict__ ow0, unsigned short* __restrict__ ow1,
    unsigned short* __restrict__ ow2, unsigned short* __restrict__ ow3)
{
  const float* src;
  unsigned short* dst;
  size_t i;
  if (blockIdx.y < 3) {
    src = blockIdx.y == 0 ? x0 : (blockIdx.y == 1 ? x1 : x2);
    dst = blockIdx.y == 0 ? ox0 : (blockIdx.y == 1 ? ox1 : ox2);
    i = ((size_t)blockIdx.x * 256 + threadIdx.x) * 8;
  } else {
    if (blockIdx.x >= 2048) return;
    size_t e = ((size_t)blockIdx.x * 256 + threadIdx.x) * 8;
    int which = (int)(e >> 20);
    size_t off = e & ((1u << 20) - 1);
    const float* ws[4] = {w0, w1, w2, w3};
    unsigned short* wd[4] = {ow0, ow1, ow2, ow3};
    src = ws[which]; dst = wd[which]; i = off;
  }
  f32x4 a = *(const f32x4*)(src + i);
  f32x4 b = *(const f32x4*)(src + i + 4);
  ushort8v h;
  h[0]=f2bf(a.x); h[1]=f2bf(a.y); h[2]=f2bf(a.z); h[3]=f2bf(a.w);
  h[4]=f2bf(b.x); h[5]=f2bf(b.y); h[6]=f2bf(b.z); h[7]=f2bf(b.w);
  *(ushort8v*)(dst + i) = h;
}

// ======== 256xBN GEMM, BK=32, 4-buffer rotation, 3-ahead counted vmcnt (T4) ========
// Buf for tile t is t&3. STAGE(t+3) targets (t+3)&3 = (t-1)&3, whose last
// reader (compute t-1) finished before the t-1 boundary barrier all waves
// passed. Boundary wait vmcnt(2*NL) keeps 2 tiles in flight (m218 formula:
// N = loads/tile x tiles-in-flight). 32 MFMA/tile hit distinct accumulators.
// 64B LDS rows with chunk-swizzle ch^((r>>1)&3): <=2-way on both sides (free).
template<int OUT, int PRESCALE, int BN>
__device__ __forceinline__ void gemm_bk32_core(
    const unsigned short* __restrict__ A,
    const unsigned short* __restrict__ Bt,
    void* __restrict__ Cout,
    unsigned short* lds, int m0, int n0)
{
  const int K = ND, N = ND;
  const int NBF = BN / 64;           // B frags per wave (4 or 2)
  const int NBL = BN / 128;          // B staging loads per thread (2 or 1)
  const int ASZ = 8192, BSZ = BN*32, SZ = ASZ + BSZ;   // elems
  const int NT = K / 32;             // 32 K-tiles
  const int tid = threadIdx.x;
  const int lane = tid & 63, wid = tid >> 6;
  const int l15 = lane & 15, lg = lane >> 4;
  const int wr = wid >> 2, wc = wid & 3;
  const float QSC = 0.125f * 1.44269504088896f;

  const unsigned short* Asrc[2];
  const unsigned short* Bsrc[2];
  int dofA[2], dofB[2];
#pragma unroll
  for (int l = 0; l < 2; ++l) {
    int cidx = l*512 + tid;
    int r = cidx >> 2;
    int ch = (cidx & 3) ^ ((r >> 1) & 3);
    Asrc[l] = A + (size_t)(m0 + r)*K + ch*8;
    dofA[l] = cidx * 8;
  }
#pragma unroll
  for (int l = 0; l < NBL; ++l) {
    int cidx = l*512 + tid;
    int r = cidx >> 2;
    int ch = (cidx & 3) ^ ((r >> 1) & 3);
    Bsrc[l] = Bt + (size_t)(n0 + r)*K + ch*8;
    dofB[l] = cidx * 8;
  }

  f32x4 acc[8][NBF] = {};

#define STAGE32(t, buf)                                                        \
  {                                                                            \
    unsigned short* d_ = lds + (buf)*SZ;                                       \
    _Pragma("unroll") for (int l = 0; l < 2; ++l)                              \
      gload16(Asrc[l] + (t)*32, d_ + dofA[l]);                                 \
    _Pragma("unroll") for (int l = 0; l < NBL; ++l)                            \
      gload16(Bsrc[l] + (t)*32, d_ + ASZ + dofB[l]);                           \
  }

  // prologue: tiles 0,1,2 into bufs 0,1,2; wait tile 0 (1,2 stay in flight)
  STAGE32(0, 0)
  STAGE32(1, 1)
  STAGE32(2, 2)
  if (NBL == 2) asm volatile("s_waitcnt vmcnt(8)" ::: "memory");
  else          asm volatile("s_waitcnt vmcnt(6)" ::: "memory");
  __builtin_amdgcn_s_barrier();

  for (int t = 0; t < NT; ++t) {
    if (t + 3 < NT) STAGE32(t + 3, (t + 3) & 3)

    const unsigned short* Abase = lds + (t & 3)*SZ;
    const unsigned short* Bbase = lds + (t & 3)*SZ + ASZ;

    short8 bfr[NBF];
#pragma unroll
    for (int nn = 0; nn < NBF; ++nn) {
      int row = wc*(BN/4) + nn*16 + l15;
      bfr[nn] = *(const short8*)(Bbase + row*32 + (lg ^ ((row >> 1) & 3))*8);
    }
#pragma unroll
    for (int mh = 0; mh < 2; ++mh) {
      short8 af[4];
#pragma unroll
      for (int mm = 0; mm < 4; ++mm) {
        int row = wr*128 + mh*64 + mm*16 + l15;
        af[mm] = *(const short8*)(Abase + row*32 + (lg ^ ((row >> 1) & 3))*8);
      }
      __builtin_amdgcn_s_setprio(1);
#pragma unroll
      for (int mm = 0; mm < 4; ++mm)
#pragma unroll
        for (int nn = 0; nn < NBF; ++nn)
          acc[mh*4+mm][nn] = __builtin_amdgcn_mfma_f32_16x16x32_bf16(
              af[mm], bfr[nn], acc[mh*4+mm][nn], 0, 0, 0);
      __builtin_amdgcn_s_setprio(0);
    }

    // boundary: tile t+1 must be visible; t+2 (and t+3 if staged) stay in flight
    if (t + 3 < NT) {
      if (NBL == 2) asm volatile("s_waitcnt vmcnt(8)" ::: "memory");
      else          asm volatile("s_waitcnt vmcnt(6)" ::: "memory");
      __builtin_amdgcn_s_barrier();
    } else if (t + 2 < NT) {
      if (NBL == 2) asm volatile("s_waitcnt vmcnt(4)" ::: "memory");
      else          asm volatile("s_waitcnt vmcnt(3)" ::: "memory");
      __builtin_amdgcn_s_barrier();
    } else if (t + 1 < NT) {
      asm volatile("s_waitcnt vmcnt(0)" ::: "memory");
      __builtin_amdgcn_s_barrier();
    }
  }
#undef STAGE32

  // epilogue: C/D layout col=lane&15, row=(lane>>4)*4+i
#pragma unroll
  for (int m = 0; m < 8; ++m)
#pragma unroll
    for (int n = 0; n < NBF; ++n)
#pragma unroll
      for (int i = 0; i < 4; ++i) {
        int row = m0 + wr*128 + m*16 + lg*4 + i;
        int col = n0 + wc*(BN/4) + n*16 + l15;
        float val = PRESCALE ? acc[m][n][i] * QSC : acc[m][n][i];
        if (OUT == 0)
          ((float*)Cout)[(size_t)row * N + col] = val;
        else if (OUT == 1)
          ((unsigned short*)Cout)[(size_t)row * N + col] = f2bf(val);
        else
          ((unsigned short*)Cout)[((size_t)((row >> 11)*1024 + col))*NS + (row & (NS-1))]
              = f2bf(val);
      }
}

// qkv: BN=256 -> LDS 4 x 32KB = 128KB, 1 block/CU; (512,1) -> 256-VGPR cap.
__global__ __launch_bounds__(512, 1) void gemm_qkv(
    const unsigned short* __restrict__ Xq, const unsigned short* __restrict__ Wq, unsigned short* Qb,
    const unsigned short* __restrict__ Xk, const unsigned short* __restrict__ Wk, unsigned short* Kb,
    const unsigned short* __restrict__ Xv, const unsigned short* __restrict__ Wv, unsigned short* VbT)
{
  __shared__ unsigned short lds[4*16384];   // 128 KB
  int flat = (blockIdx.z * 32 + blockIdx.y) * 4 + blockIdx.x;
  int swz = xcd_swz(flat, 384);
  int z = swz >> 7, rem = swz & 127;
  int m0 = (rem >> 2) * 256, n0 = (rem & 3) * 256;
  if (z == 0)      gemm_bk32_core<1,1,256>(Xq, Wq, Qb,  lds, m0, n0);
  else if (z == 1) gemm_bk32_core<1,0,256>(Xk, Wk, Kb,  lds, m0, n0);
  else             gemm_bk32_core<2,0,256>(Xv, Wv, VbT, lds, m0, n0);
}

// o: BN=128 -> LDS 4 x 24KB = 96KB; 256 blocks = 1/CU.
__global__ __launch_bounds__(512, 1) void gemm_o(
    const unsigned short* __restrict__ A, const unsigned short* __restrict__ Bt, float* C)
{
  __shared__ unsigned short lds[4*12288];   // 96 KB
  int flat = blockIdx.y * 8 + blockIdx.x;
  int swz = xcd_swz(flat, 256);
  gemm_bk32_core<0,0,128>(A, Bt, C, lds, (swz >> 3) * 256, (swz & 7) * 128);
}

// ---------------- Flash attention (R9/R15/R16 structure — best measured, 94 us) ----
__global__ __launch_bounds__(256, 2) void flash_attn(
    const unsigned short* __restrict__ Qb,   // pre-scaled by 0.125*log2e
    const unsigned short* __restrict__ Kb,
    const unsigned short* __restrict__ VT,   // [B*H*64][2048] = V^T per head
    unsigned short* __restrict__ O)          // bf16 [8192][1024]
{
  __shared__ unsigned short Kt[2][64*64];    // [g=d-group][s-row][8 elems]
  __shared__ unsigned short Vt[2][64*64];    // [g=s-group][d-row][8 elems]
  const int tid = threadIdx.x, lane = tid & 63, wid = tid >> 6;
  const int l31 = lane & 31, hi = lane >> 5;
  int flat = blockIdx.y * 8 + blockIdx.x;
  int swz = xcd_swz(flat, 512);
  const int bh = swz >> 3, b = bh >> 4, h = bh & 15;
  const int q0 = (swz & 7) * 256 + wid * 64;

  const unsigned short* Kp[2]; const unsigned short* Vp[2]; int dofs[2];
#pragma unroll
  for (int p = 0; p < 2; ++p) {
    int slot = tid + p*256;
    int g = slot >> 6, r = slot & 63;
    Kp[p] = Kb + ((size_t)(b*NS + r))*ND + h*64 + g*8;
    Vp[p] = VT + ((size_t)(bh*64 + r))*NS + g*8;
    dofs[p] = slot * 8;
  }

  short8 qf[2][4];
#pragma unroll
  for (int qs = 0; qs < 2; ++qs)
#pragma unroll
    for (int ks = 0; ks < 4; ++ks)
      qf[qs][ks] = *(const short8*)(Qb + (size_t)(b*NS + q0 + qs*32 + l31)*ND + h*64 + ks*16 + hi*8);

  f32x16 oacc[2][2] = {};
  float lsum[2] = {0.f, 0.f};

#pragma unroll
  for (int p = 0; p < 2; ++p) {
    gload16(Kp[p], &Kt[0][dofs[p]]);
    gload16(Vp[p], &Vt[0][dofs[p]]);
  }
  __syncthreads();

  for (int t = 0; t < NS/64; ++t) {
    const int cur = t & 1;
    if (t + 1 < NS/64) {
#pragma unroll
      for (int p = 0; p < 2; ++p) {
        gload16(Kp[p] + (size_t)(t+1)*64*ND, &Kt[cur^1][dofs[p]]);
        gload16(Vp[p] + (t+1)*64,            &Vt[cur^1][dofs[p]]);
      }
    }
    const char* Kc = (const char*)Kt[cur];
    const char* Vc = (const char*)Vt[cur];

    short8 pa[2][2][2];
    float rs[2] = {0.f, 0.f};

#pragma unroll
    for (int n = 0; n < 2; ++n) {
      f32x16 st[2] = {};
      const int r = n*32 + l31;
      __builtin_amdgcn_s_setprio(1);
#pragma unroll
      for (int ks = 0; ks < 4; ++ks) {
        short8 kf = *(const short8*)(Kc + (((2*ks + hi) << 10) + r*16));
        st[0] = __builtin_amdgcn_mfma_f32_32x32x16_bf16(kf, qf[0][ks], st[0], 0, 0, 0);
        st[1] = __builtin_amdgcn_mfma_f32_32x32x16_bf16(kf, qf[1][ks], st[1], 0, 0, 0);
      }
      __builtin_amdgcn_s_setprio(0);
#pragma unroll
      for (int qs = 0; qs < 2; ++qs) {
        float lrs = 0.f;
#pragma unroll
        for (int e = 0; e < 16; ++e) {
          float p = __builtin_amdgcn_exp2f(st[qs][e]);
          st[qs][e] = p;
          lrs += p;
        }
        rs[qs] += lrs;
        uint32_t w[4][2];
#pragma unroll
        for (int e = 0; e < 4; ++e) {
          asm("v_cvt_pk_bf16_f32 %0, %1, %2"
              : "=v"(w[e][0]) : "v"(st[qs][4*e+0]), "v"(st[qs][4*e+1]));
          asm("v_cvt_pk_bf16_f32 %0, %1, %2"
              : "=v"(w[e][1]) : "v"(st[qs][4*e+2]), "v"(st[qs][4*e+3]));
        }
#pragma unroll
        for (int ksl = 0; ksl < 2; ++ksl) {
          uint32_t a0 = w[2*ksl][0], b0 = w[2*ksl+1][0];
          uint32_t a1 = w[2*ksl][1], b1 = w[2*ksl+1][1];
          asm("v_permlane32_swap_b32 %0, %1" : "+v"(a0), "+v"(b0));
          asm("v_permlane32_swap_b32 %0, %1" : "+v"(a1), "+v"(b1));
          union { uint32_t u[4]; short8 s; } f;
          f.u[0] = a0; f.u[1] = a1; f.u[2] = b0; f.u[3] = b1;
          pa[qs][n][ksl] = f.s;
        }
      }
    }
#pragma unroll
    for (int qs = 0; qs < 2; ++qs) {
      rs[qs] += __shfl_xor(rs[qs], 32);
      lsum[qs] += rs[qs];
    }

    __builtin_amdgcn_s_setprio(1);
#pragma unroll
    for (int d = 0; d < 2; ++d) {
      const int dr = d*32 + l31;
#pragma unroll
      for (int n = 0; n < 2; ++n)
#pragma unroll
        for (int ksl = 0; ksl < 2; ++ksl) {
          const int g = n*4 + ksl*2 + hi;
          short8 vf = *(const short8*)(Vc + ((g << 10) + dr*16));
          oacc[0][d] = __builtin_amdgcn_mfma_f32_32x32x16_bf16(pa[0][n][ksl], vf, oacc[0][d], 0, 0, 0);
          oacc[1][d] = __builtin_amdgcn_mfma_f32_32x32x16_bf16(pa[1][n][ksl], vf, oacc[1][d], 0, 0, 0);
        }
    }
    __builtin_amdgcn_s_setprio(0);
    __syncthreads();
  }

#pragma unroll
  for (int qs = 0; qs < 2; ++qs) {
    float linv[16];
#pragma unroll
    for (int r = 0; r < 16; ++r)
      linv[r] = 1.0f / __shfl(lsum[qs], (r & 3) + 8*(r >> 2) + 4*hi);
#pragma unroll
    for (int d = 0; d < 2; ++d)
#pragma unroll
      for (int r = 0; r < 16; ++r) {
        int qrow = q0 + qs*32 + (r & 3) + 8*(r >> 2) + 4*hi;
        O[(size_t)(b*NS + qrow)*ND + h*64 + d*32 + l31] = f2bf(oacc[qs][d][r] * linv[r]);
      }
  }
}

// ---------------- launch ----------------
extern "C" void kernel_launch(void* const* d_in, const int* in_sizes, int n_in,
                              void* d_out, int out_size, void* d_ws, size_t ws_size,
                              hipStream_t stream) {
  const float* q  = (const float*)d_in[0];
  const float* k  = (const float*)d_in[1];
  const float* v  = (const float*)d_in[2];
  const float* wq = (const float*)d_in[3];
  const float* wk = (const float*)d_in[4];
  const float* wv = (const float*)d_in[5];
  const float* wo = (const float*)d_in[6];

  unsigned short* Wq = (unsigned short*)d_ws;
  unsigned short* Wk = Wq + (size_t)ND*ND;
  unsigned short* Wv = Wk + (size_t)ND*ND;
  unsigned short* Wo = Wv + (size_t)ND*ND;
  unsigned short* Xq = Wo + (size_t)ND*ND;
  unsigned short* Xk = Xq + (size_t)NM*ND;
  unsigned short* Xv = Xk + (size_t)NM*ND;
  unsigned short* Qb = Xv + (size_t)NM*ND;
  unsigned short* Kb = Qb + (size_t)NM*ND;
  unsigned short* VbT = (unsigned short*)d_out;   // scratch in d_out; rewritten by gemm_o
  unsigned short* Ob  = Xq;                       // alias: Xq dead after qkv launch

  convert_all<<<dim3(NM*ND/(256*8), 4), 256, 0, stream>>>(
      q, k, v, wq, wk, wv, wo, Xq, Xk, Xv, Wq, Wk, Wv, Wo);

  gemm_qkv<<<dim3(4, 32, 3), 512, 0, stream>>>(Xq, Wq, Qb, Xk, Wk, Kb, Xv, Wv, VbT);

  flash_attn<<<dim3(8, 64), 256, 0, stream>>>(Qb, Kb, VbT, Ob);

  gemm_o<<<dim3(8, 32), 512, 0, stream>>>(Ob, Wo, (float*)d_out);
}

// Round 19
// 200.144 us; speedup vs baseline: 1.0178x; 1.0178x over previous
//
#include <hip/hip_runtime.h>
#include <stdint.h>

#define NB 4
#define NS 2048
#define ND 1024
#define NH 16
#define NDK 64
#define NM (NB*NS)   // 8192 rows total

typedef __attribute__((ext_vector_type(8))) short short8;
typedef __attribute__((ext_vector_type(8))) unsigned short ushort8v;
typedef __attribute__((ext_vector_type(4))) float f32x4;
typedef __attribute__((ext_vector_type(16))) float f32x16;

__device__ __forceinline__ unsigned short f2bf(float f) {
  union { float f; uint32_t u; } v; v.f = f;
  uint32_t u = v.u;
  return (unsigned short)((u + 0x7FFFu + ((u >> 16) & 1u)) >> 16);
}

__device__ __forceinline__ uint32_t cvtpk(float lo, float hi) {
  uint32_t r;
  asm("v_cvt_pk_bf16_f32 %0, %1, %2" : "=v"(r) : "v"(lo), "v"(hi));
  return r;
}

__device__ __forceinline__ void gload16(const void* g, void* l) {
  __builtin_amdgcn_global_load_lds(
      (const __attribute__((address_space(1))) void*)g,
      (__attribute__((address_space(3))) void*)l, 16, 0, 0);
}

// T1: bijective XCD swizzle (requires nwg % 8 == 0)
__device__ __forceinline__ int xcd_swz(int flat, int nwg) {
  return (flat & 7) * (nwg >> 3) + (flat >> 3);
}

// ---------------- weights-only conversion fp32 -> bf16 (4 x 1M elems) ----------------
__global__ void convert_weights(
    const float* __restrict__ w0, const float* __restrict__ w1,
    const float* __restrict__ w2, const float* __restrict__ w3,
    unsigned short* __restrict__ ow0, unsigned short* __restrict__ ow1,
    unsigned short* __restrict__ ow2, unsigned short* __restrict__ ow3)
{
  size_t e = ((size_t)blockIdx.x * 256 + threadIdx.x) * 8;
  int which = (int)(e >> 20);
  size_t i = e & ((1u << 20) - 1);
  const float* ws[4] = {w0, w1, w2, w3};
  unsigned short* wd[4] = {ow0, ow1, ow2, ow3};
  const float* src = ws[which];
  unsigned short* dst = wd[which];
  f32x4 a = *(const f32x4*)(src + i);
  f32x4 b = *(const f32x4*)(src + i + 4);
  ushort8v h;
  h[0]=f2bf(a.x); h[1]=f2bf(a.y); h[2]=f2bf(a.z); h[3]=f2bf(a.w);
  h[4]=f2bf(b.x); h[5]=f2bf(b.y); h[6]=f2bf(b.z); h[7]=f2bf(b.w);
  *(ushort8v*)(dst + i) = h;
}

// ====== QKV GEMM: A = raw fp32 X (DMA-staged, cvt at frag-load), B = bf16 W ======
// BM=256, BN=256, BK=32, 3-buf/2-ahead counted vmcnt. Per buf: A 32KB fp32 +
// B 16KB bf16 = 48KB; 3 bufs = 144KB (1 block/CU). A rows are 128B (8 chunks
// of 4 fp32), slot = ch^(r&7): DMA-linear write conflict-free, frag read 2-way.
// A-frag = 2x ds_read_b128 (f32x4) + 4x v_cvt_pk_bf16_f32 -> short8.
template<int OUT, int PRESCALE>
__device__ __forceinline__ void gemm_a32_core(
    const float* __restrict__ X,
    const unsigned short* __restrict__ Wt,
    void* __restrict__ Cout,
    char* lds, int m0, int n0)
{
  const int K = ND, N = ND;
  const int SZB = 49152;             // bytes per buf (32KB A + 16KB B)
  const int NT = K / 32;             // 32 K-tiles
  const int tid = threadIdx.x;
  const int lane = tid & 63, wid = tid >> 6;
  const int l15 = lane & 15, lg = lane >> 4;
  const int wr = wid >> 2, wc = wid & 3;
  const float QSC = 0.125f * 1.44269504088896f;

  // A staging: 4 x 16B per thread; cidx = l*512+tid in [0,2048): r=cidx>>3,
  // slot=cidx&7 holds global fp32-chunk slot^(r&7).
  const float* Asrc[4];
  int dofA[4];
#pragma unroll
  for (int l = 0; l < 4; ++l) {
    int cidx = l*512 + tid;
    int r = cidx >> 3;
    int c = (cidx & 7) ^ (r & 7);
    Asrc[l] = X + (size_t)(m0 + r)*K + c*4;
    dofA[l] = cidx * 16;             // byte offset in A area
  }
  // B staging: 2 x 16B per thread; cidx in [0,1024): r=cidx>>2, slot=cidx&3
  // holds bf16-chunk slot^((r>>1)&3).
  const unsigned short* Bsrc[2];
  int dofB[2];
#pragma unroll
  for (int l = 0; l < 2; ++l) {
    int cidx = l*512 + tid;
    int r = cidx >> 2;
    int c = (cidx & 3) ^ ((r >> 1) & 3);
    Bsrc[l] = Wt + (size_t)(n0 + r)*K + c*8;
    dofB[l] = cidx * 16;             // byte offset in B area
  }

  f32x4 acc[8][4] = {};

#define STAGEQ(t, buf)                                                         \
  {                                                                            \
    char* d_ = lds + (buf)*SZB;                                                \
    _Pragma("unroll") for (int l = 0; l < 4; ++l)                              \
      gload16(Asrc[l] + (t)*32, d_ + dofA[l]);                                 \
    _Pragma("unroll") for (int l = 0; l < 2; ++l)                              \
      gload16(Bsrc[l] + (t)*32, d_ + 32768 + dofB[l]);                         \
  }

  // prologue: tiles 0,1 into bufs 0,1; wait tile 0's 6 loads (tile 1 in flight)
  STAGEQ(0, 0)
  STAGEQ(1, 1)
  asm volatile("s_waitcnt vmcnt(6)" ::: "memory");
  __builtin_amdgcn_s_barrier();

  int b0 = 0;
  for (int t = 0; t < NT; ++t) {
    if (t + 2 < NT) {
      int nb = b0 + 2; if (nb >= 3) nb -= 3;
      STAGEQ(t + 2, nb)
    }
    const char* Ab = lds + b0*SZB;
    const unsigned short* Bb = (const unsigned short*)(lds + b0*SZB + 32768);

    short8 bfr[4];
#pragma unroll
    for (int nn = 0; nn < 4; ++nn) {
      int row = wc*64 + nn*16 + l15;
      bfr[nn] = *(const short8*)(Bb + row*32 + (lg ^ ((row >> 1) & 3))*8);
    }
#pragma unroll
    for (int mh = 0; mh < 2; ++mh) {
      short8 af[4];
#pragma unroll
      for (int mm = 0; mm < 4; ++mm) {
        int row = wr*128 + mh*64 + mm*16 + l15;
        const char* Ar = Ab + row*128;
        int c0 = (2*lg) ^ (row & 7), c1 = (2*lg + 1) ^ (row & 7);
        f32x4 a0 = *(const f32x4*)(Ar + c0*16);
        f32x4 a1 = *(const f32x4*)(Ar + c1*16);
        union { uint32_t u[4]; short8 s; } f;
        f.u[0] = cvtpk(a0.x, a0.y); f.u[1] = cvtpk(a0.z, a0.w);
        f.u[2] = cvtpk(a1.x, a1.y); f.u[3] = cvtpk(a1.z, a1.w);
        af[mm] = f.s;
      }
      __builtin_amdgcn_s_setprio(1);
#pragma unroll
      for (int mm = 0; mm < 4; ++mm)
#pragma unroll
        for (int nn = 0; nn < 4; ++nn)
          acc[mh*4+mm][nn] = __builtin_amdgcn_mfma_f32_16x16x32_bf16(
              af[mm], bfr[nn], acc[mh*4+mm][nn], 0, 0, 0);
      __builtin_amdgcn_s_setprio(0);
    }

    if (t + 2 < NT) {
      asm volatile("s_waitcnt vmcnt(6)" ::: "memory");   // t+1 landed, t+2 flying
      __builtin_amdgcn_s_barrier();
    } else if (t + 1 < NT) {
      asm volatile("s_waitcnt vmcnt(0)" ::: "memory");
      __builtin_amdgcn_s_barrier();
    }
    b0 = (b0 + 1 == 3) ? 0 : b0 + 1;
  }
#undef STAGEQ

  // epilogue: C/D layout col=lane&15, row=(lane>>4)*4+i
#pragma unroll
  for (int m = 0; m < 8; ++m)
#pragma unroll
    for (int n = 0; n < 4; ++n)
#pragma unroll
      for (int i = 0; i < 4; ++i) {
        int row = m0 + wr*128 + m*16 + lg*4 + i;
        int col = n0 + wc*64 + n*16 + l15;
        float val = PRESCALE ? acc[m][n][i] * QSC : acc[m][n][i];
        if (OUT == 1)
          ((unsigned short*)Cout)[(size_t)row * N + col] = f2bf(val);
        else
          ((unsigned short*)Cout)[((size_t)((row >> 11)*1024 + col))*NS + (row & (NS-1))]
              = f2bf(val);
      }
}

__global__ __launch_bounds__(512, 1) void gemm_qkv(
    const float* __restrict__ Xq, const unsigned short* __restrict__ Wq, unsigned short* Qb,
    const float* __restrict__ Xk, const unsigned short* __restrict__ Wk, unsigned short* Kb,
    const float* __restrict__ Xv, const unsigned short* __restrict__ Wv, unsigned short* VbT)
{
  __shared__ char lds[3*49152];   // 144 KB
  int flat = (blockIdx.z * 32 + blockIdx.y) * 4 + blockIdx.x;
  int swz = xcd_swz(flat, 384);
  int z = swz >> 7, rem = swz & 127;
  int m0 = (rem >> 2) * 256, n0 = (rem & 3) * 256;
  if (z == 0)      gemm_a32_core<1,1>(Xq, Wq, Qb,  lds, m0, n0);
  else if (z == 1) gemm_a32_core<1,0>(Xk, Wk, Kb,  lds, m0, n0);
  else             gemm_a32_core<2,0>(Xv, Wv, VbT, lds, m0, n0);
}

// ====== O GEMM: all-bf16, BM=128, BN=128, BK=32, 3-buf, 512 blocks = 2/CU ======
__global__ __launch_bounds__(512, 2) void gemm_o(
    const unsigned short* __restrict__ A, const unsigned short* __restrict__ Bt, float* C)
{
  __shared__ unsigned short lds[3*8192];   // 48 KB (3 bufs x (8KB A + 8KB B))
  const int K = ND, N = ND;
  const int SZ = 8192;               // elems per buf
  const int NT = K / 32;
  const int tid = threadIdx.x;
  const int lane = tid & 63, wid = tid >> 6;
  const int l15 = lane & 15, lg = lane >> 4;
  const int wr = wid >> 2, wc = wid & 3;
  int flat = blockIdx.y * 8 + blockIdx.x;
  int swz = xcd_swz(flat, 512);
  const int m0 = (swz >> 3) * 128, n0 = (swz & 7) * 128;

  const unsigned short* Asrc;
  const unsigned short* Bsrc;
  int dofA, dofB;
  {
    int r = tid >> 2;
    int c = (tid & 3) ^ ((r >> 1) & 3);
    Asrc = A  + (size_t)(m0 + r)*K + c*8;
    Bsrc = Bt + (size_t)(n0 + r)*K + c*8;
    dofA = tid * 8;
    dofB = 4096 + tid * 8;
  }

  f32x4 acc[4][2] = {};

#define STAGEO(t, buf)                                                         \
  {                                                                            \
    unsigned short* d_ = lds + (buf)*SZ;                                       \
    gload16(Asrc + (t)*32, d_ + dofA);                                         \
    gload16(Bsrc + (t)*32, d_ + dofB);                                         \
  }

  STAGEO(0, 0)
  STAGEO(1, 1)
  asm volatile("s_waitcnt vmcnt(2)" ::: "memory");
  __builtin_amdgcn_s_barrier();

  int b0 = 0;
  for (int t = 0; t < NT; ++t) {
    if (t + 2 < NT) {
      int nb = b0 + 2; if (nb >= 3) nb -= 3;
      STAGEO(t + 2, nb)
    }
    const unsigned short* Abase = lds + b0*SZ;
    const unsigned short* Bbase = lds + b0*SZ + 4096;

    short8 bfr[2];
#pragma unroll
    for (int nn = 0; nn < 2; ++nn) {
      int row = wc*32 + nn*16 + l15;
      bfr[nn] = *(const short8*)(Bbase + row*32 + (lg ^ ((row >> 1) & 3))*8);
    }
    short8 af[4];
#pragma unroll
    for (int mm = 0; mm < 4; ++mm) {
      int row = wr*64 + mm*16 + l15;
      af[mm] = *(const short8*)(Abase + row*32 + (lg ^ ((row >> 1) & 3))*8);
    }
    __builtin_amdgcn_s_setprio(1);
#pragma unroll
    for (int mm = 0; mm < 4; ++mm)
#pragma unroll
      for (int nn = 0; nn < 2; ++nn)
        acc[mm][nn] = __builtin_amdgcn_mfma_f32_16x16x32_bf16(
            af[mm], bfr[nn], acc[mm][nn], 0, 0, 0);
    __builtin_amdgcn_s_setprio(0);

    if (t + 2 < NT) {
      asm volatile("s_waitcnt vmcnt(2)" ::: "memory");
      __builtin_amdgcn_s_barrier();
    } else if (t + 1 < NT) {
      asm volatile("s_waitcnt vmcnt(0)" ::: "memory");
      __builtin_amdgcn_s_barrier();
    }
    b0 = (b0 + 1 == 3) ? 0 : b0 + 1;
  }
#undef STAGEO

#pragma unroll
  for (int m = 0; m < 4; ++m)
#pragma unroll
    for (int n = 0; n < 2; ++n)
#pragma unroll
      for (int i = 0; i < 4; ++i) {
        int row = m0 + wr*64 + m*16 + lg*4 + i;
        int col = n0 + wc*32 + n*16 + l15;
        C[(size_t)row * N + col] = acc[m][n][i];
      }
}

// ---------------- Flash attention (R9/R16 structure — best measured, 94 us) --------
__global__ __launch_bounds__(256, 2) void flash_attn(
    const unsigned short* __restrict__ Qb,   // pre-scaled by 0.125*log2e
    const unsigned short* __restrict__ Kb,
    const unsigned short* __restrict__ VT,   // [B*H*64][2048] = V^T per head
    unsigned short* __restrict__ O)          // bf16 [8192][1024]
{
  __shared__ unsigned short Kt[2][64*64];    // [g=d-group][s-row][8 elems]
  __shared__ unsigned short Vt[2][64*64];    // [g=s-group][d-row][8 elems]
  const int tid = threadIdx.x, lane = tid & 63, wid = tid >> 6;
  const int l31 = lane & 31, hi = lane >> 5;
  int flat = blockIdx.y * 8 + blockIdx.x;
  int swz = xcd_swz(flat, 512);
  const int bh = swz >> 3, b = bh >> 4, h = bh & 15;
  const int q0 = (swz & 7) * 256 + wid * 64;

  const unsigned short* Kp[2]; const unsigned short* Vp[2]; int dofs[2];
#pragma unroll
  for (int p = 0; p < 2; ++p) {
    int slot = tid + p*256;
    int g = slot >> 6, r = slot & 63;
    Kp[p] = Kb + ((size_t)(b*NS + r))*ND + h*64 + g*8;
    Vp[p] = VT + ((size_t)(bh*64 + r))*NS + g*8;
    dofs[p] = slot * 8;
  }

  short8 qf[2][4];
#pragma unroll
  for (int qs = 0; qs < 2; ++qs)
#pragma unroll
    for (int ks = 0; ks < 4; ++ks)
      qf[qs][ks] = *(const short8*)(Qb + (size_t)(b*NS + q0 + qs*32 + l31)*ND + h*64 + ks*16 + hi*8);

  f32x16 oacc[2][2] = {};
  float lsum[2] = {0.f, 0.f};

#pragma unroll
  for (int p = 0; p < 2; ++p) {
    gload16(Kp[p], &Kt[0][dofs[p]]);
    gload16(Vp[p], &Vt[0][dofs[p]]);
  }
  __syncthreads();

  for (int t = 0; t < NS/64; ++t) {
    const int cur = t & 1;
    if (t + 1 < NS/64) {
#pragma unroll
      for (int p = 0; p < 2; ++p) {
        gload16(Kp[p] + (size_t)(t+1)*64*ND, &Kt[cur^1][dofs[p]]);
        gload16(Vp[p] + (t+1)*64,            &Vt[cur^1][dofs[p]]);
      }
    }
    const char* Kc = (const char*)Kt[cur];
    const char* Vc = (const char*)Vt[cur];

    short8 pa[2][2][2];
    float rs[2] = {0.f, 0.f};

#pragma unroll
    for (int n = 0; n < 2; ++n) {
      f32x16 st[2] = {};
      const int r = n*32 + l31;
      __builtin_amdgcn_s_setprio(1);
#pragma unroll
      for (int ks = 0; ks < 4; ++ks) {
        short8 kf = *(const short8*)(Kc + (((2*ks + hi) << 10) + r*16));
        st[0] = __builtin_amdgcn_mfma_f32_32x32x16_bf16(kf, qf[0][ks], st[0], 0, 0, 0);
        st[1] = __builtin_amdgcn_mfma_f32_32x32x16_bf16(kf, qf[1][ks], st[1], 0, 0, 0);
      }
      __builtin_amdgcn_s_setprio(0);
#pragma unroll
      for (int qs = 0; qs < 2; ++qs) {
        float lrs = 0.f;
#pragma unroll
        for (int e = 0; e < 16; ++e) {
          float p = __builtin_amdgcn_exp2f(st[qs][e]);
          st[qs][e] = p;
          lrs += p;
        }
        rs[qs] += lrs;
        uint32_t w[4][2];
#pragma unroll
        for (int e = 0; e < 4; ++e) {
          w[e][0] = cvtpk(st[qs][4*e+0], st[qs][4*e+1]);
          w[e][1] = cvtpk(st[qs][4*e+2], st[qs][4*e+3]);
        }
#pragma unroll
        for (int ksl = 0; ksl < 2; ++ksl) {
          uint32_t a0 = w[2*ksl][0], b0 = w[2*ksl+1][0];
          uint32_t a1 = w[2*ksl][1], b1 = w[2*ksl+1][1];
          asm("v_permlane32_swap_b32 %0, %1" : "+v"(a0), "+v"(b0));
          asm("v_permlane32_swap_b32 %0, %1" : "+v"(a1), "+v"(b1));
          union { uint32_t u[4]; short8 s; } f;
          f.u[0] = a0; f.u[1] = a1; f.u[2] = b0; f.u[3] = b1;
          pa[qs][n][ksl] = f.s;
        }
      }
    }
#pragma unroll
    for (int qs = 0; qs < 2; ++qs) {
      rs[qs] += __shfl_xor(rs[qs], 32);
      lsum[qs] += rs[qs];
    }

    __builtin_amdgcn_s_setprio(1);
#pragma unroll
    for (int d = 0; d < 2; ++d) {
      const int dr = d*32 + l31;
#pragma unroll
      for (int n = 0; n < 2; ++n)
#pragma unroll
        for (int ksl = 0; ksl < 2; ++ksl) {
          const int g = n*4 + ksl*2 + hi;
          short8 vf = *(const short8*)(Vc + ((g << 10) + dr*16));
          oacc[0][d] = __builtin_amdgcn_mfma_f32_32x32x16_bf16(pa[0][n][ksl], vf, oacc[0][d], 0, 0, 0);
          oacc[1][d] = __builtin_amdgcn_mfma_f32_32x32x16_bf16(pa[1][n][ksl], vf, oacc[1][d], 0, 0, 0);
        }
    }
    __builtin_amdgcn_s_setprio(0);
    __syncthreads();
  }

#pragma unroll
  for (int qs = 0; qs < 2; ++qs) {
    float linv[16];
#pragma unroll
    for (int r = 0; r < 16; ++r)
      linv[r] = 1.0f / __shfl(lsum[qs], (r & 3) + 8*(r >> 2) + 4*hi);
#pragma unroll
    for (int d = 0; d < 2; ++d)
#pragma unroll
      for (int r = 0; r < 16; ++r) {
        int qrow = q0 + qs*32 + (r & 3) + 8*(r >> 2) + 4*hi;
        O[(size_t)(b*NS + qrow)*ND + h*64 + d*32 + l31] = f2bf(oacc[qs][d][r] * linv[r]);
      }
  }
}

// ---------------- launch ----------------
extern "C" void kernel_launch(void* const* d_in, const int* in_sizes, int n_in,
                              void* d_out, int out_size, void* d_ws, size_t ws_size,
                              hipStream_t stream) {
  const float* q  = (const float*)d_in[0];
  const float* k  = (const float*)d_in[1];
  const float* v  = (const float*)d_in[2];
  const float* wq = (const float*)d_in[3];
  const float* wk = (const float*)d_in[4];
  const float* wv = (const float*)d_in[5];
  const float* wo = (const float*)d_in[6];

  unsigned short* Wq = (unsigned short*)d_ws;
  unsigned short* Wk = Wq + (size_t)ND*ND;
  unsigned short* Wv = Wk + (size_t)ND*ND;
  unsigned short* Wo = Wv + (size_t)ND*ND;
  unsigned short* Qb = Wo + (size_t)ND*ND;
  unsigned short* Kb = Qb + (size_t)NM*ND;
  unsigned short* Ob = Kb + (size_t)NM*ND;        // 56 MB total ws use
  unsigned short* VbT = (unsigned short*)d_out;   // scratch in d_out; rewritten by gemm_o

  convert_weights<<<2048, 256, 0, stream>>>(wq, wk, wv, wo, Wq, Wk, Wv, Wo);

  gemm_qkv<<<dim3(4, 32, 3), 512, 0, stream>>>(q, Wq, Qb, k, Wk, Kb, v, Wv, VbT);

  flash_attn<<<dim3(8, 64), 256, 0, stream>>>(Qb, Kb, VbT, Ob);

  gemm_o<<<dim3(8, 64), 512, 0, stream>>>(Ob, Wo, (float*)d_out);
}